// Round 2
// baseline (425.376 us; speedup 1.0000x reference)
//
#include <hip/hip_runtime.h>
#include <hip/hip_bf16.h>
#include <stdint.h>

#define B_   32
#define C_   512
#define HW_  3136
#define HID_ 128
#define PT   64     // pixels per block tile
#define XP   72     // xlds pitch (bf16 elems)
#define HP   136    // hlds pitch
#define EPS_ 1e-5f

using frag8 = __attribute__((ext_vector_type(8))) short;  // 8 bf16 (4 VGPRs)
using f32x4 = __attribute__((ext_vector_type(4))) float;  // 4 fp32 acc

__device__ __forceinline__ short f2bf(float f) {
    union { float f; uint32_t u; } v; v.f = f;
    uint32_t u = v.u;
    u += 0x7fffu + ((u >> 16) & 1u);   // RNE
    return (short)(u >> 16);
}

// ---------------------------------------------------------------------------
// Prep: fp32 weights -> bf16 panels; one A-frag load per wave is a single
// fully-coalesced 1KB read: panel(mt,kt) is 16x32 bf16, element (i, 8q+j) at
// offset ((q*16+i)*8 + j). Also folds BN into scale/shift.
// ---------------------------------------------------------------------------
__global__ __launch_bounds__(256) void prep_kernel(
    const float* __restrict__ w1_rgb, const float* __restrict__ w2_rgb,
    const float* __restrict__ w1_inf, const float* __restrict__ w2_inf,
    const float* __restrict__ rm_rgb, const float* __restrict__ rv_rgb,
    const float* __restrict__ g_rgb,  const float* __restrict__ b_rgb,
    const float* __restrict__ rm_inf, const float* __restrict__ rv_inf,
    const float* __restrict__ g_inf,  const float* __restrict__ b_inf,
    short* __restrict__ w1p_rgb, short* __restrict__ w1p_inf,
    short* __restrict__ w2p_rgb, short* __restrict__ w2p_inf,
    float* __restrict__ ss)
{
    int t = blockIdx.x * 256 + threadIdx.x;   // 0 .. 65535
    int p = t >> 9, w = t & 511;
    int q = w >> 7, r = (w >> 3) & 15, j = w & 7;
    {   // w1: M=128, K=512 -> 8 x 16 panels
        int mt = p >> 4, kt = p & 15;
        int m = mt * 16 + r, k = kt * 32 + q * 8 + j;
        w1p_rgb[t] = f2bf(w1_rgb[m * C_ + k]);
        w1p_inf[t] = f2bf(w1_inf[m * C_ + k]);
    }
    {   // w2: M=512, K=128 -> 32 x 4 panels
        int mt = p >> 2, kt = p & 3;
        int m = mt * 16 + r, k = kt * 32 + q * 8 + j;
        w2p_rgb[t] = f2bf(w2_rgb[m * HID_ + k]);
        w2p_inf[t] = f2bf(w2_inf[m * HID_ + k]);
    }
    if (t < 128) {
        float sc = g_rgb[t] * rsqrtf(rv_rgb[t] + EPS_);
        ss[t] = sc; ss[128 + t] = b_rgb[t] - rm_rgb[t] * sc;
    } else if (t < 256) {
        int i = t - 128;
        float sc = g_inf[i] * rsqrtf(rv_inf[i] + EPS_);
        ss[256 + i] = sc; ss[384 + i] = b_inf[i] - rm_inf[i] * sc;
    }
}

// ---------------------------------------------------------------------------
// Fused: per block (sample b, 64-pixel tile):
//   stage1: h(128x64) = w1_sel @ x-tile (K=512), BN+ReLU -> hlds bf16
//           -- software-pipelined: x-chunk k+1 global loads fly while MFMA
//              runs on chunk k; double-buffered xlds, ONE barrier per chunk
//   stage2: out(512x64) = w2_sel @ h (K=128) -> fp32 global
// ---------------------------------------------------------------------------
__global__ __launch_bounds__(256, 4) void fused_kernel(
    const float* __restrict__ x, const int* __restrict__ mod,
    const short* __restrict__ w1p_rgb, const short* __restrict__ w1p_inf,
    const short* __restrict__ w2p_rgb, const short* __restrict__ w2p_inf,
    const float* __restrict__ ss, float* __restrict__ out)
{
    __shared__ short xlds[2][PT * XP];   // double-buffered x chunk (64px x 64ch)
    __shared__ short hlds[PT * HP];      // [pixel][hid(128)] pitch 136

    const int tid  = threadIdx.x;
    const int lane = tid & 63;
    const int wave = tid >> 6;
    const int i16  = lane & 15;   // frag col index
    const int q    = lane >> 4;   // frag quad
    const int b    = blockIdx.y;
    const int p0   = blockIdx.x * PT;

    const int is_rgb = (mod[b] == 1);
    const short* __restrict__ w1p = is_rgb ? w1p_rgb : w1p_inf;
    const short* __restrict__ w2p = is_rgb ? w2p_rgb : w2p_inf;
    const float* __restrict__ scale = ss + (is_rgb ? 0 : 256);
    const float* __restrict__ shift = scale + 128;

    // ---- Stage 1: wave handles hid rows [wave*32, wave*32+32) = 2 M-tiles ----
    f32x4 acc1[2][4];
    #pragma unroll
    for (int mt = 0; mt < 2; ++mt)
        #pragma unroll
        for (int nt = 0; nt < 4; ++nt)
            acc1[mt][nt] = (f32x4){0.f, 0.f, 0.f, 0.f};

    const int px = tid & 63;          // staging: this thread's pixel
    const int cg = tid >> 6;          // staging: channel group (16 ch each)
    const float* xbase = x + ((size_t)b * C_) * HW_ + p0 + px;

    // prologue: issue chunk-0 loads into registers (fp32, converted at use)
    float xr[16];
    #pragma unroll
    for (int it = 0; it < 4; ++it) {
        int c = cg * 16 + it * 4;
        xr[it * 4 + 0] = xbase[(size_t)(c + 0) * HW_];
        xr[it * 4 + 1] = xbase[(size_t)(c + 1) * HW_];
        xr[it * 4 + 2] = xbase[(size_t)(c + 2) * HW_];
        xr[it * 4 + 3] = xbase[(size_t)(c + 3) * HW_];
    }

    #pragma unroll 2
    for (int kc = 0; kc < C_; kc += 64) {
        short* xw = &xlds[(kc >> 6) & 1][0];

        // convert + write current chunk (waitcnt for xr lands here, one full
        // MFMA phase after the loads were issued)
        #pragma unroll
        for (int it = 0; it < 4; ++it) {
            int c = cg * 16 + it * 4;
            short4 pk = make_short4(f2bf(xr[it * 4 + 0]), f2bf(xr[it * 4 + 1]),
                                    f2bf(xr[it * 4 + 2]), f2bf(xr[it * 4 + 3]));
            *(short4*)(&xw[px * XP + c]) = pk;
        }

        // issue NEXT chunk's global loads; they stay in flight across the
        // barrier (plain reg loads: __syncthreads drains lgkmcnt only)
        if (kc + 64 < C_) {
            #pragma unroll
            for (int it = 0; it < 4; ++it) {
                int c = kc + 64 + cg * 16 + it * 4;
                xr[it * 4 + 0] = xbase[(size_t)(c + 0) * HW_];
                xr[it * 4 + 1] = xbase[(size_t)(c + 1) * HW_];
                xr[it * 4 + 2] = xbase[(size_t)(c + 2) * HW_];
                xr[it * 4 + 3] = xbase[(size_t)(c + 3) * HW_];
            }
        }

        // this chunk's A-frags (global, L2-resident panels)
        frag8 af[2][2];
        #pragma unroll
        for (int kk = 0; kk < 2; ++kk) {
            int kt = (kc >> 5) + kk;
            #pragma unroll
            for (int mt = 0; mt < 2; ++mt) {
                int mtg = wave * 2 + mt;
                af[kk][mt] = *(const frag8*)(w1p + ((mtg * 16 + kt) << 9) + lane * 8);
            }
        }

        __syncthreads();   // ds_writes visible; prefetch loads still in flight

        #pragma unroll
        for (int kk = 0; kk < 2; ++kk) {
            frag8 bfr[4];
            #pragma unroll
            for (int nt = 0; nt < 4; ++nt)
                bfr[nt] = *(const frag8*)(&xw[(nt * 16 + i16) * XP + kk * 32 + q * 8]);
            #pragma unroll
            for (int mt = 0; mt < 2; ++mt)
                #pragma unroll
                for (int nt = 0; nt < 4; ++nt)
                    acc1[mt][nt] = __builtin_amdgcn_mfma_f32_16x16x32_bf16(
                        af[kk][mt], bfr[nt], acc1[mt][nt], 0, 0, 0);
        }
        // no trailing barrier: double-buffer. Iter k+2's write to this buffer
        // is ordered after barrier(k+1), which is after all reads of iter k.
    }

    // ---- BN + ReLU -> hlds (bf16, pixel-major) ----
    #pragma unroll
    for (int mt = 0; mt < 2; ++mt) {
        int mbase = wave * 32 + mt * 16 + q * 4;
        float s0 = scale[mbase + 0], s1 = scale[mbase + 1];
        float s2 = scale[mbase + 2], s3 = scale[mbase + 3];
        float h0 = shift[mbase + 0], h1 = shift[mbase + 1];
        float h2 = shift[mbase + 2], h3 = shift[mbase + 3];
        #pragma unroll
        for (int nt = 0; nt < 4; ++nt) {
            int p = nt * 16 + i16;
            float v0 = fmaxf(acc1[mt][nt][0] * s0 + h0, 0.f);
            float v1 = fmaxf(acc1[mt][nt][1] * s1 + h1, 0.f);
            float v2 = fmaxf(acc1[mt][nt][2] * s2 + h2, 0.f);
            float v3 = fmaxf(acc1[mt][nt][3] * s3 + h3, 0.f);
            short4 pk = make_short4(f2bf(v0), f2bf(v1), f2bf(v2), f2bf(v3));
            *(short4*)(&hlds[p * HP + mbase]) = pk;
        }
    }
    __syncthreads();

    // ---- Stage 2: out(512x64); wave does 4 M-tiles x 4 N-tiles per half ----
    #pragma unroll 1
    for (int half = 0; half < 2; ++half) {
        f32x4 acc2[4][4];
        #pragma unroll
        for (int mt = 0; mt < 4; ++mt)
            #pragma unroll
            for (int nt = 0; nt < 4; ++nt)
                acc2[mt][nt] = (f32x4){0.f, 0.f, 0.f, 0.f};

        #pragma unroll
        for (int kt = 0; kt < 4; ++kt) {
            frag8 af[4], bfr[4];
            #pragma unroll
            for (int mt = 0; mt < 4; ++mt) {
                int mtg = half * 16 + wave * 4 + mt;
                af[mt] = *(const frag8*)(w2p + ((mtg * 4 + kt) << 9) + lane * 8);
            }
            #pragma unroll
            for (int nt = 0; nt < 4; ++nt)
                bfr[nt] = *(const frag8*)(&hlds[(nt * 16 + i16) * HP + kt * 32 + q * 8]);
            #pragma unroll
            for (int mt = 0; mt < 4; ++mt)
                #pragma unroll
                for (int nt = 0; nt < 4; ++nt)
                    acc2[mt][nt] = __builtin_amdgcn_mfma_f32_16x16x32_bf16(
                        af[mt], bfr[nt], acc2[mt][nt], 0, 0, 0);
        }
        // store fp32
        #pragma unroll
        for (int mt = 0; mt < 4; ++mt) {
            int mrow = (half * 16 + wave * 4 + mt) * 16 + q * 4;
            #pragma unroll
            for (int nt = 0; nt < 4; ++nt) {
                int col = p0 + nt * 16 + i16;
                float* op = out + ((size_t)(b * C_ + mrow)) * HW_ + col;
                op[0 * HW_] = acc2[mt][nt][0];
                op[1 * HW_] = acc2[mt][nt][1];
                op[2 * HW_] = acc2[mt][nt][2];
                op[3 * HW_] = acc2[mt][nt][3];
            }
        }
    }
}

extern "C" void kernel_launch(void* const* d_in, const int* in_sizes, int n_in,
                              void* d_out, int out_size, void* d_ws, size_t ws_size,
                              hipStream_t stream) {
    const float* x      = (const float*)d_in[0];
    const int*   mod    = (const int*)d_in[1];
    const float* w1_rgb = (const float*)d_in[2];
    const float* rm_rgb = (const float*)d_in[3];
    const float* rv_rgb = (const float*)d_in[4];
    const float* g_rgb  = (const float*)d_in[5];
    const float* b_rgb  = (const float*)d_in[6];
    const float* w2_rgb = (const float*)d_in[7];
    const float* w1_inf = (const float*)d_in[8];
    const float* rm_inf = (const float*)d_in[9];
    const float* rv_inf = (const float*)d_in[10];
    const float* g_inf  = (const float*)d_in[11];
    const float* b_inf  = (const float*)d_in[12];
    const float* w2_inf = (const float*)d_in[13];
    float* out = (float*)d_out;

    char* ws = (char*)d_ws;
    short* w1p_rgb = (short*)(ws + 0);
    short* w1p_inf = (short*)(ws + 131072);
    short* w2p_rgb = (short*)(ws + 262144);
    short* w2p_inf = (short*)(ws + 393216);
    float* ss      = (float*)(ws + 524288);   // 512 floats

    prep_kernel<<<256, 256, 0, stream>>>(
        w1_rgb, w2_rgb, w1_inf, w2_inf,
        rm_rgb, rv_rgb, g_rgb, b_rgb,
        rm_inf, rv_inf, g_inf, b_inf,
        w1p_rgb, w1p_inf, w2p_rgb, w2p_inf, ss);

    dim3 grid(HW_ / PT, B_);
    fused_kernel<<<grid, 256, 0, stream>>>(
        x, mod, w1p_rgb, w1p_inf, w2p_rgb, w2p_inf, ss, out);
}

// Round 5
// 388.054 us; speedup vs baseline: 1.0962x; 1.0962x over previous
//
#include <hip/hip_runtime.h>
#include <hip/hip_bf16.h>
#include <stdint.h>

#define B_   32
#define C_   512
#define HW_  3136
#define HID_ 128
#define PT   64     // pixels per block tile
#define XP   72     // xlds pitch (bf16 elems)
#define HP   136    // hlds pitch
#define EPS_ 1e-5f

using frag8 = __attribute__((ext_vector_type(8))) short;  // 8 bf16 (4 VGPRs)
using f32x4 = __attribute__((ext_vector_type(4))) float;  // 4 fp32 acc

__device__ __forceinline__ short f2bf(float f) {
    union { float f; uint32_t u; } v; v.f = f;
    uint32_t u = v.u;
    u += 0x7fffu + ((u >> 16) & 1u);   // RNE
    return (short)(u >> 16);
}

// ---------------------------------------------------------------------------
// Prep: fp32 weights -> bf16 panels; one A-frag load per wave is a single
// fully-coalesced 1KB read: panel(mt,kt) is 16x32 bf16, element (i, 8q+j) at
// offset ((q*16+i)*8 + j). Also folds BN into scale/shift.
// ---------------------------------------------------------------------------
__global__ __launch_bounds__(256) void prep_kernel(
    const float* __restrict__ w1_rgb, const float* __restrict__ w2_rgb,
    const float* __restrict__ w1_inf, const float* __restrict__ w2_inf,
    const float* __restrict__ rm_rgb, const float* __restrict__ rv_rgb,
    const float* __restrict__ g_rgb,  const float* __restrict__ b_rgb,
    const float* __restrict__ rm_inf, const float* __restrict__ rv_inf,
    const float* __restrict__ g_inf,  const float* __restrict__ b_inf,
    short* __restrict__ w1p_rgb, short* __restrict__ w1p_inf,
    short* __restrict__ w2p_rgb, short* __restrict__ w2p_inf,
    float* __restrict__ ss)
{
    int t = blockIdx.x * 256 + threadIdx.x;   // 0 .. 65535
    int p = t >> 9, w = t & 511;
    int q = w >> 7, r = (w >> 3) & 15, j = w & 7;
    {   // w1: M=128, K=512 -> 8 x 16 panels
        int mt = p >> 4, kt = p & 15;
        int m = mt * 16 + r, k = kt * 32 + q * 8 + j;
        w1p_rgb[t] = f2bf(w1_rgb[m * C_ + k]);
        w1p_inf[t] = f2bf(w1_inf[m * C_ + k]);
    }
    {   // w2: M=512, K=128 -> 32 x 4 panels
        int mt = p >> 2, kt = p & 3;
        int m = mt * 16 + r, k = kt * 32 + q * 8 + j;
        w2p_rgb[t] = f2bf(w2_rgb[m * HID_ + k]);
        w2p_inf[t] = f2bf(w2_inf[m * HID_ + k]);
    }
    if (t < 128) {
        float sc = g_rgb[t] * rsqrtf(rv_rgb[t] + EPS_);
        ss[t] = sc; ss[128 + t] = b_rgb[t] - rm_rgb[t] * sc;
    } else if (t < 256) {
        int i = t - 128;
        float sc = g_inf[i] * rsqrtf(rv_inf[i] + EPS_);
        ss[256 + i] = sc; ss[384 + i] = b_inf[i] - rm_inf[i] * sc;
    }
}

// ---------------------------------------------------------------------------
// Fused: per block (sample b, 64-pixel tile):
//   stage1: h(128x64) = w1_sel @ x-tile (K=512), BN+ReLU -> hlds bf16
//           -- software-pipelined: x-chunk k+1 global loads fly while MFMA
//              runs on chunk k; double-buffered xlds, ONE barrier per chunk
//   stage2: out(512x64) = w2_sel @ h (K=128) -> fp32 global
//   LDS: hlds ALIASES the two xlds buffers (stage-1 fully drains xlds before
//        the post-loop barrier) -> 18432 B total, LDS never the occupancy cap
// ---------------------------------------------------------------------------
__global__ __launch_bounds__(256) void fused_kernel(
    const float* __restrict__ x, const int* __restrict__ mod,
    const short* __restrict__ w1p_rgb, const short* __restrict__ w1p_inf,
    const short* __restrict__ w2p_rgb, const short* __restrict__ w2p_inf,
    const float* __restrict__ ss, float* __restrict__ out)
{
    __shared__ short smem[2 * PT * XP];  // 2 x-chunk buffers; reused as hlds
    short* hlds = smem;                  // [pixel][hid(128)] pitch 136; 8704<=9216

    const int tid  = threadIdx.x;
    const int lane = tid & 63;
    const int wave = tid >> 6;
    const int i16  = lane & 15;   // frag col index
    const int q    = lane >> 4;   // frag quad
    const int b    = blockIdx.y;
    const int p0   = blockIdx.x * PT;

    const int is_rgb = (mod[b] == 1);
    const short* __restrict__ w1p = is_rgb ? w1p_rgb : w1p_inf;
    const short* __restrict__ w2p = is_rgb ? w2p_rgb : w2p_inf;
    const float* __restrict__ scale = ss + (is_rgb ? 0 : 256);
    const float* __restrict__ shift = scale + 128;

    // ---- Stage 1: wave handles hid rows [wave*32, wave*32+32) = 2 M-tiles ----
    f32x4 acc1[2][4];
    #pragma unroll
    for (int mt = 0; mt < 2; ++mt)
        #pragma unroll
        for (int nt = 0; nt < 4; ++nt)
            acc1[mt][nt] = (f32x4){0.f, 0.f, 0.f, 0.f};

    const int px = tid & 63;          // staging: this thread's pixel
    const int cg = tid >> 6;          // staging: channel group (16 ch each)
    const float* xbase = x + ((size_t)b * C_) * HW_ + p0 + px;

    // prologue: issue chunk-0 loads into registers (fp32, converted at use)
    float xr[16];
    #pragma unroll
    for (int it = 0; it < 4; ++it) {
        int c = cg * 16 + it * 4;
        xr[it * 4 + 0] = xbase[(size_t)(c + 0) * HW_];
        xr[it * 4 + 1] = xbase[(size_t)(c + 1) * HW_];
        xr[it * 4 + 2] = xbase[(size_t)(c + 2) * HW_];
        xr[it * 4 + 3] = xbase[(size_t)(c + 3) * HW_];
    }

    #pragma unroll 2
    for (int kc = 0; kc < C_; kc += 64) {
        short* xw = &smem[((kc >> 6) & 1) * (PT * XP)];

        // convert + write current chunk (waitcnt for xr lands here, one full
        // MFMA phase after the loads were issued)
        #pragma unroll
        for (int it = 0; it < 4; ++it) {
            int c = cg * 16 + it * 4;
            short4 pk = make_short4(f2bf(xr[it * 4 + 0]), f2bf(xr[it * 4 + 1]),
                                    f2bf(xr[it * 4 + 2]), f2bf(xr[it * 4 + 3]));
            *(short4*)(&xw[px * XP + c]) = pk;
        }

        // issue NEXT chunk's global loads; they stay in flight across the
        // barrier (plain reg loads: __syncthreads drains lgkmcnt only)
        if (kc + 64 < C_) {
            #pragma unroll
            for (int it = 0; it < 4; ++it) {
                int c = kc + 64 + cg * 16 + it * 4;
                xr[it * 4 + 0] = xbase[(size_t)(c + 0) * HW_];
                xr[it * 4 + 1] = xbase[(size_t)(c + 1) * HW_];
                xr[it * 4 + 2] = xbase[(size_t)(c + 2) * HW_];
                xr[it * 4 + 3] = xbase[(size_t)(c + 3) * HW_];
            }
        }

        // this chunk's A-frags (global, L2-resident panels)
        frag8 af[2][2];
        #pragma unroll
        for (int kk = 0; kk < 2; ++kk) {
            int kt = (kc >> 5) + kk;
            #pragma unroll
            for (int mt = 0; mt < 2; ++mt) {
                int mtg = wave * 2 + mt;
                af[kk][mt] = *(const frag8*)(w1p + ((mtg * 16 + kt) << 9) + lane * 8);
            }
        }

        __syncthreads();   // ds_writes visible; prefetch loads still in flight

        #pragma unroll
        for (int kk = 0; kk < 2; ++kk) {
            frag8 bfr[4];
            #pragma unroll
            for (int nt = 0; nt < 4; ++nt)
                bfr[nt] = *(const frag8*)(&xw[(nt * 16 + i16) * XP + kk * 32 + q * 8]);
            #pragma unroll
            for (int mt = 0; mt < 2; ++mt)
                #pragma unroll
                for (int nt = 0; nt < 4; ++nt)
                    acc1[mt][nt] = __builtin_amdgcn_mfma_f32_16x16x32_bf16(
                        af[kk][mt], bfr[nt], acc1[mt][nt], 0, 0, 0);
        }
        // no trailing barrier: double-buffer. Iter k+2's write to this buffer
        // is ordered after barrier(k+1), which is after all reads of iter k.
    }

    // all waves must be done reading smem-as-xlds before hlds overwrites it
    __syncthreads();

    // ---- BN + ReLU -> hlds (bf16, pixel-major) ----
    #pragma unroll
    for (int mt = 0; mt < 2; ++mt) {
        int mbase = wave * 32 + mt * 16 + q * 4;
        float s0 = scale[mbase + 0], s1 = scale[mbase + 1];
        float s2 = scale[mbase + 2], s3 = scale[mbase + 3];
        float h0 = shift[mbase + 0], h1 = shift[mbase + 1];
        float h2 = shift[mbase + 2], h3 = shift[mbase + 3];
        #pragma unroll
        for (int nt = 0; nt < 4; ++nt) {
            int p = nt * 16 + i16;
            float v0 = fmaxf(acc1[mt][nt][0] * s0 + h0, 0.f);
            float v1 = fmaxf(acc1[mt][nt][1] * s1 + h1, 0.f);
            float v2 = fmaxf(acc1[mt][nt][2] * s2 + h2, 0.f);
            float v3 = fmaxf(acc1[mt][nt][3] * s3 + h3, 0.f);
            short4 pk = make_short4(f2bf(v0), f2bf(v1), f2bf(v2), f2bf(v3));
            *(short4*)(&hlds[p * HP + mbase]) = pk;
        }
    }
    __syncthreads();

    // ---- Stage 2: out(512x64); wave does 4 M-tiles x 4 N-tiles per half ----
    #pragma unroll 1
    for (int half = 0; half < 2; ++half) {
        f32x4 acc2[4][4];
        #pragma unroll
        for (int mt = 0; mt < 4; ++mt)
            #pragma unroll
            for (int nt = 0; nt < 4; ++nt)
                acc2[mt][nt] = (f32x4){0.f, 0.f, 0.f, 0.f};

        #pragma unroll
        for (int kt = 0; kt < 4; ++kt) {
            frag8 af[4], bfr[4];
            #pragma unroll
            for (int mt = 0; mt < 4; ++mt) {
                int mtg = half * 16 + wave * 4 + mt;
                af[mt] = *(const frag8*)(w2p + ((mtg * 4 + kt) << 9) + lane * 8);
            }
            #pragma unroll
            for (int nt = 0; nt < 4; ++nt)
                bfr[nt] = *(const frag8*)(&hlds[(nt * 16 + i16) * HP + kt * 32 + q * 8]);
            #pragma unroll
            for (int mt = 0; mt < 4; ++mt)
                #pragma unroll
                for (int nt = 0; nt < 4; ++nt)
                    acc2[mt][nt] = __builtin_amdgcn_mfma_f32_16x16x32_bf16(
                        af[mt], bfr[nt], acc2[mt][nt], 0, 0, 0);
        }
        // store fp32
        #pragma unroll
        for (int mt = 0; mt < 4; ++mt) {
            int mrow = (half * 16 + wave * 4 + mt) * 16 + q * 4;
            #pragma unroll
            for (int nt = 0; nt < 4; ++nt) {
                int col = p0 + nt * 16 + i16;
                float* op = out + ((size_t)(b * C_ + mrow)) * HW_ + col;
                op[0 * HW_] = acc2[mt][nt][0];
                op[1 * HW_] = acc2[mt][nt][1];
                op[2 * HW_] = acc2[mt][nt][2];
                op[3 * HW_] = acc2[mt][nt][3];
            }
        }
    }
}

extern "C" void kernel_launch(void* const* d_in, const int* in_sizes, int n_in,
                              void* d_out, int out_size, void* d_ws, size_t ws_size,
                              hipStream_t stream) {
    const float* x      = (const float*)d_in[0];
    const int*   mod    = (const int*)d_in[1];
    const float* w1_rgb = (const float*)d_in[2];
    const float* rm_rgb = (const float*)d_in[3];
    const float* rv_rgb = (const float*)d_in[4];
    const float* g_rgb  = (const float*)d_in[5];
    const float* b_rgb  = (const float*)d_in[6];
    const float* w2_rgb = (const float*)d_in[7];
    const float* w1_inf = (const float*)d_in[8];
    const float* rm_inf = (const float*)d_in[9];
    const float* rv_inf = (const float*)d_in[10];
    const float* g_inf  = (const float*)d_in[11];
    const float* b_inf  = (const float*)d_in[12];
    const float* w2_inf = (const float*)d_in[13];
    float* out = (float*)d_out;

    char* ws = (char*)d_ws;
    short* w1p_rgb = (short*)(ws + 0);
    short* w1p_inf = (short*)(ws + 131072);
    short* w2p_rgb = (short*)(ws + 262144);
    short* w2p_inf = (short*)(ws + 393216);
    float* ss      = (float*)(ws + 524288);   // 512 floats

    prep_kernel<<<256, 256, 0, stream>>>(
        w1_rgb, w2_rgb, w1_inf, w2_inf,
        rm_rgb, rv_rgb, g_rgb, b_rgb,
        rm_inf, rv_inf, g_inf, b_inf,
        w1p_rgb, w1p_inf, w2p_rgb, w2p_inf, ss);

    dim3 grid(HW_ / PT, B_);
    fused_kernel<<<grid, 256, 0, stream>>>(
        x, mod, w1p_rgb, w1p_inf, w2p_rgb, w2p_inf, ss, out);
}

// Round 9
// 387.530 us; speedup vs baseline: 1.0977x; 1.0014x over previous
//
#include <hip/hip_runtime.h>
#include <hip/hip_bf16.h>
#include <stdint.h>

#define B_   32
#define C_   512
#define HW_  3136
#define HID_ 128
#define PT   64     // pixels per block tile
#define XP   72     // xlds pitch (bf16 elems)
#define HP   136    // hlds pitch
#define EPS_ 1e-5f

using frag8 = __attribute__((ext_vector_type(8))) short;  // 8 bf16 (4 VGPRs)
using f32x4 = __attribute__((ext_vector_type(4))) float;  // 4 fp32 acc

__device__ __forceinline__ short f2bf(float f) {
    union { float f; uint32_t u; } v; v.f = f;
    uint32_t u = v.u;
    u += 0x7fffu + ((u >> 16) & 1u);   // RNE
    return (short)(u >> 16);
}

// Barrier that does NOT drain vmem: ds_writes made visible (lgkmcnt(0)),
// but in-flight global prefetch loads survive the barrier (T4, learn_hip).
// __syncthreads() would emit s_waitcnt vmcnt(0) and kill the pipeline.
#define BARRIER_KEEP_VMEM() do {                                  \
    asm volatile("s_waitcnt lgkmcnt(0)" ::: "memory");            \
    __builtin_amdgcn_s_barrier();                                 \
    asm volatile("" ::: "memory");                                \
} while (0)

// ---------------------------------------------------------------------------
// Prep: fp32 weights -> bf16 panels; one A-frag load per wave is a single
// fully-coalesced 1KB read: panel(mt,kt) is 16x32 bf16, element (i, 8q+j) at
// offset ((q*16+i)*8 + j). Also folds BN into scale/shift.
// ---------------------------------------------------------------------------
__global__ __launch_bounds__(256) void prep_kernel(
    const float* __restrict__ w1_rgb, const float* __restrict__ w2_rgb,
    const float* __restrict__ w1_inf, const float* __restrict__ w2_inf,
    const float* __restrict__ rm_rgb, const float* __restrict__ rv_rgb,
    const float* __restrict__ g_rgb,  const float* __restrict__ b_rgb,
    const float* __restrict__ rm_inf, const float* __restrict__ rv_inf,
    const float* __restrict__ g_inf,  const float* __restrict__ b_inf,
    short* __restrict__ w1p_rgb, short* __restrict__ w1p_inf,
    short* __restrict__ w2p_rgb, short* __restrict__ w2p_inf,
    float* __restrict__ ss)
{
    int t = blockIdx.x * 256 + threadIdx.x;   // 0 .. 65535
    int p = t >> 9, w = t & 511;
    int q = w >> 7, r = (w >> 3) & 15, j = w & 7;
    {   // w1: M=128, K=512 -> 8 x 16 panels
        int mt = p >> 4, kt = p & 15;
        int m = mt * 16 + r, k = kt * 32 + q * 8 + j;
        w1p_rgb[t] = f2bf(w1_rgb[m * C_ + k]);
        w1p_inf[t] = f2bf(w1_inf[m * C_ + k]);
    }
    {   // w2: M=512, K=128 -> 32 x 4 panels
        int mt = p >> 2, kt = p & 3;
        int m = mt * 16 + r, k = kt * 32 + q * 8 + j;
        w2p_rgb[t] = f2bf(w2_rgb[m * HID_ + k]);
        w2p_inf[t] = f2bf(w2_inf[m * HID_ + k]);
    }
    if (t < 128) {
        float sc = g_rgb[t] * rsqrtf(rv_rgb[t] + EPS_);
        ss[t] = sc; ss[128 + t] = b_rgb[t] - rm_rgb[t] * sc;
    } else if (t < 256) {
        int i = t - 128;
        float sc = g_inf[i] * rsqrtf(rv_inf[i] + EPS_);
        ss[256 + i] = sc; ss[384 + i] = b_inf[i] - rm_inf[i] * sc;
    }
}

// ---------------------------------------------------------------------------
// Fused: per block (sample b, 64-pixel tile):
//   stage1: h(128x64) = w1_sel @ x-tile (K=512), BN+ReLU -> hlds bf16
//           -- software-pipelined: x-chunk k+1 global loads issued before the
//              barrier and — because the barrier is raw s_barrier with
//              lgkmcnt-only drain — they stay in flight through the MFMA
//              phase, drained only at next iteration's converts.
//   stage2: out(512x64) = w2_sel @ h (K=128) -> fp32 global
//   LDS: hlds ALIASES the two xlds buffers (stage-1 fully drains xlds before
//        the post-loop barrier) -> 18432 B total, LDS never the occupancy cap
// ---------------------------------------------------------------------------
__global__ __launch_bounds__(256) void fused_kernel(
    const float* __restrict__ x, const int* __restrict__ mod,
    const short* __restrict__ w1p_rgb, const short* __restrict__ w1p_inf,
    const short* __restrict__ w2p_rgb, const short* __restrict__ w2p_inf,
    const float* __restrict__ ss, float* __restrict__ out)
{
    __shared__ short smem[2 * PT * XP];  // 2 x-chunk buffers; reused as hlds
    short* hlds = smem;                  // [pixel][hid(128)] pitch 136; 8704<=9216

    const int tid  = threadIdx.x;
    const int lane = tid & 63;
    const int wave = tid >> 6;
    const int i16  = lane & 15;   // frag col index
    const int q    = lane >> 4;   // frag quad
    const int b    = blockIdx.y;
    const int p0   = blockIdx.x * PT;

    const int is_rgb = (mod[b] == 1);
    const short* __restrict__ w1p = is_rgb ? w1p_rgb : w1p_inf;
    const short* __restrict__ w2p = is_rgb ? w2p_rgb : w2p_inf;
    const float* __restrict__ scale = ss + (is_rgb ? 0 : 256);
    const float* __restrict__ shift = scale + 128;

    // ---- Stage 1: wave handles hid rows [wave*32, wave*32+32) = 2 M-tiles ----
    f32x4 acc1[2][4];
    #pragma unroll
    for (int mt = 0; mt < 2; ++mt)
        #pragma unroll
        for (int nt = 0; nt < 4; ++nt)
            acc1[mt][nt] = (f32x4){0.f, 0.f, 0.f, 0.f};

    const int px = tid & 63;          // staging: this thread's pixel
    const int cg = tid >> 6;          // staging: channel group (16 ch each)
    const float* xbase = x + ((size_t)b * C_) * HW_ + p0 + px;

    // prologue: issue chunk-0 loads into registers (fp32, converted at use)
    float xr[16];
    #pragma unroll
    for (int it = 0; it < 4; ++it) {
        int c = cg * 16 + it * 4;
        xr[it * 4 + 0] = xbase[(size_t)(c + 0) * HW_];
        xr[it * 4 + 1] = xbase[(size_t)(c + 1) * HW_];
        xr[it * 4 + 2] = xbase[(size_t)(c + 2) * HW_];
        xr[it * 4 + 3] = xbase[(size_t)(c + 3) * HW_];
    }

    #pragma unroll 2
    for (int kc = 0; kc < C_; kc += 64) {
        short* xw = &smem[((kc >> 6) & 1) * (PT * XP)];

        // convert + write current chunk; the compiler inserts a PRECISE
        // vmcnt wait here for the xr loads (issued one full iteration ago)
        #pragma unroll
        for (int it = 0; it < 4; ++it) {
            int c = cg * 16 + it * 4;
            short4 pk = make_short4(f2bf(xr[it * 4 + 0]), f2bf(xr[it * 4 + 1]),
                                    f2bf(xr[it * 4 + 2]), f2bf(xr[it * 4 + 3]));
            *(short4*)(&xw[px * XP + c]) = pk;
        }

        // issue NEXT chunk's global loads; with the raw barrier below they
        // genuinely stay in flight across it (no vmcnt(0) drain)
        if (kc + 64 < C_) {
            #pragma unroll
            for (int it = 0; it < 4; ++it) {
                int c = kc + 64 + cg * 16 + it * 4;
                xr[it * 4 + 0] = xbase[(size_t)(c + 0) * HW_];
                xr[it * 4 + 1] = xbase[(size_t)(c + 1) * HW_];
                xr[it * 4 + 2] = xbase[(size_t)(c + 2) * HW_];
                xr[it * 4 + 3] = xbase[(size_t)(c + 3) * HW_];
            }
        }

        // this chunk's A-frags (global, L2-resident panels)
        frag8 af[2][2];
        #pragma unroll
        for (int kk = 0; kk < 2; ++kk) {
            int kt = (kc >> 5) + kk;
            #pragma unroll
            for (int mt = 0; mt < 2; ++mt) {
                int mtg = wave * 2 + mt;
                af[kk][mt] = *(const frag8*)(w1p + ((mtg * 16 + kt) << 9) + lane * 8);
            }
        }

        // ds_writes visible; prefetch loads SURVIVE the barrier
        BARRIER_KEEP_VMEM();

        #pragma unroll
        for (int kk = 0; kk < 2; ++kk) {
            frag8 bfr[4];
            #pragma unroll
            for (int nt = 0; nt < 4; ++nt)
                bfr[nt] = *(const frag8*)(&xw[(nt * 16 + i16) * XP + kk * 32 + q * 8]);
            #pragma unroll
            for (int mt = 0; mt < 2; ++mt)
                #pragma unroll
                for (int nt = 0; nt < 4; ++nt)
                    acc1[mt][nt] = __builtin_amdgcn_mfma_f32_16x16x32_bf16(
                        af[kk][mt], bfr[nt], acc1[mt][nt], 0, 0, 0);
        }
        // no trailing barrier: double-buffer. Iter k+2's write to this buffer
        // is ordered after barrier(k+1), and each wave's lgkmcnt(0) before
        // barrier(k+1) covers its iter-k LDS reads.
    }

    // all waves must be done reading smem-as-xlds before hlds overwrites it
    // (full drain is fine here; nothing useful is in flight on the last iter)
    __syncthreads();

    // ---- BN + ReLU -> hlds (bf16, pixel-major) ----
    #pragma unroll
    for (int mt = 0; mt < 2; ++mt) {
        int mbase = wave * 32 + mt * 16 + q * 4;
        float s0 = scale[mbase + 0], s1 = scale[mbase + 1];
        float s2 = scale[mbase + 2], s3 = scale[mbase + 3];
        float h0 = shift[mbase + 0], h1 = shift[mbase + 1];
        float h2 = shift[mbase + 2], h3 = shift[mbase + 3];
        #pragma unroll
        for (int nt = 0; nt < 4; ++nt) {
            int p = nt * 16 + i16;
            float v0 = fmaxf(acc1[mt][nt][0] * s0 + h0, 0.f);
            float v1 = fmaxf(acc1[mt][nt][1] * s1 + h1, 0.f);
            float v2 = fmaxf(acc1[mt][nt][2] * s2 + h2, 0.f);
            float v3 = fmaxf(acc1[mt][nt][3] * s3 + h3, 0.f);
            short4 pk = make_short4(f2bf(v0), f2bf(v1), f2bf(v2), f2bf(v3));
            *(short4*)(&hlds[p * HP + mbase]) = pk;
        }
    }
    __syncthreads();

    // ---- Stage 2: out(512x64); wave does 4 M-tiles x 4 N-tiles per half ----
    #pragma unroll 1
    for (int half = 0; half < 2; ++half) {
        f32x4 acc2[4][4];
        #pragma unroll
        for (int mt = 0; mt < 4; ++mt)
            #pragma unroll
            for (int nt = 0; nt < 4; ++nt)
                acc2[mt][nt] = (f32x4){0.f, 0.f, 0.f, 0.f};

        #pragma unroll
        for (int kt = 0; kt < 4; ++kt) {
            frag8 af[4], bfr[4];
            #pragma unroll
            for (int mt = 0; mt < 4; ++mt) {
                int mtg = half * 16 + wave * 4 + mt;
                af[mt] = *(const frag8*)(w2p + ((mtg * 4 + kt) << 9) + lane * 8);
            }
            #pragma unroll
            for (int nt = 0; nt < 4; ++nt)
                bfr[nt] = *(const frag8*)(&hlds[(nt * 16 + i16) * HP + kt * 32 + q * 8]);
            #pragma unroll
            for (int mt = 0; mt < 4; ++mt)
                #pragma unroll
                for (int nt = 0; nt < 4; ++nt)
                    acc2[mt][nt] = __builtin_amdgcn_mfma_f32_16x16x32_bf16(
                        af[mt], bfr[nt], acc2[mt][nt], 0, 0, 0);
        }
        // store fp32
        #pragma unroll
        for (int mt = 0; mt < 4; ++mt) {
            int mrow = (half * 16 + wave * 4 + mt) * 16 + q * 4;
            #pragma unroll
            for (int nt = 0; nt < 4; ++nt) {
                int col = p0 + nt * 16 + i16;
                float* op = out + ((size_t)(b * C_ + mrow)) * HW_ + col;
                op[0 * HW_] = acc2[mt][nt][0];
                op[1 * HW_] = acc2[mt][nt][1];
                op[2 * HW_] = acc2[mt][nt][2];
                op[3 * HW_] = acc2[mt][nt][3];
            }
        }
    }
}

extern "C" void kernel_launch(void* const* d_in, const int* in_sizes, int n_in,
                              void* d_out, int out_size, void* d_ws, size_t ws_size,
                              hipStream_t stream) {
    const float* x      = (const float*)d_in[0];
    const int*   mod    = (const int*)d_in[1];
    const float* w1_rgb = (const float*)d_in[2];
    const float* rm_rgb = (const float*)d_in[3];
    const float* rv_rgb = (const float*)d_in[4];
    const float* g_rgb  = (const float*)d_in[5];
    const float* b_rgb  = (const float*)d_in[6];
    const float* w2_rgb = (const float*)d_in[7];
    const float* w1_inf = (const float*)d_in[8];
    const float* rm_inf = (const float*)d_in[9];
    const float* rv_inf = (const float*)d_in[10];
    const float* g_inf  = (const float*)d_in[11];
    const float* b_inf  = (const float*)d_in[12];
    const float* w2_inf = (const float*)d_in[13];
    float* out = (float*)d_out;

    char* ws = (char*)d_ws;
    short* w1p_rgb = (short*)(ws + 0);
    short* w1p_inf = (short*)(ws + 131072);
    short* w2p_rgb = (short*)(ws + 262144);
    short* w2p_inf = (short*)(ws + 393216);
    float* ss      = (float*)(ws + 524288);   // 512 floats

    prep_kernel<<<256, 256, 0, stream>>>(
        w1_rgb, w2_rgb, w1_inf, w2_inf,
        rm_rgb, rv_rgb, g_rgb, b_rgb,
        rm_inf, rv_inf, g_inf, b_inf,
        w1p_rgb, w1p_inf, w2p_rgb, w2p_inf, ss);

    dim3 grid(HW_ / PT, B_);
    fused_kernel<<<grid, 256, 0, stream>>>(
        x, mod, w1p_rgb, w1p_inf, w2p_rgb, w2p_inf, ss, out);
}

// Round 11
// 382.940 us; speedup vs baseline: 1.1108x; 1.0120x over previous
//
#include <hip/hip_runtime.h>
#include <hip/hip_bf16.h>
#include <stdint.h>

#define B_   32
#define C_   512
#define HW_  3136
#define HID_ 128
#define PT   64     // pixels per block tile
#define XP   72     // xlds pitch (bf16 elems)
#define HP   136    // hlds pitch
#define EPS_ 1e-5f

using frag8 = __attribute__((ext_vector_type(8))) short;  // 8 bf16 (4 VGPRs)
using f32x4 = __attribute__((ext_vector_type(4))) float;  // 4 fp32 acc

__device__ __forceinline__ short f2bf(float f) {
    union { float f; uint32_t u; } v; v.f = f;
    uint32_t u = v.u;
    u += 0x7fffu + ((u >> 16) & 1u);   // RNE
    return (short)(u >> 16);
}

// Barrier that does NOT drain vmem: ds_writes made visible (lgkmcnt(0)),
// but in-flight global prefetch loads survive the barrier (T4, learn_hip).
#define BARRIER_KEEP_VMEM() do {                                  \
    asm volatile("s_waitcnt lgkmcnt(0)" ::: "memory");            \
    __builtin_amdgcn_s_barrier();                                 \
    asm volatile("" ::: "memory");                                \
} while (0)

// ---------------------------------------------------------------------------
// Prep: fp32 weights -> bf16 panels; one A-frag load per wave is a single
// fully-coalesced 1KB read: panel(mt,kt) is 16x32 bf16, element (i, 8q+j) at
// offset ((q*16+i)*8 + j). Also folds BN into scale/shift.
// ---------------------------------------------------------------------------
__global__ __launch_bounds__(256) void prep_kernel(
    const float* __restrict__ w1_rgb, const float* __restrict__ w2_rgb,
    const float* __restrict__ w1_inf, const float* __restrict__ w2_inf,
    const float* __restrict__ rm_rgb, const float* __restrict__ rv_rgb,
    const float* __restrict__ g_rgb,  const float* __restrict__ b_rgb,
    const float* __restrict__ rm_inf, const float* __restrict__ rv_inf,
    const float* __restrict__ g_inf,  const float* __restrict__ b_inf,
    short* __restrict__ w1p_rgb, short* __restrict__ w1p_inf,
    short* __restrict__ w2p_rgb, short* __restrict__ w2p_inf,
    float* __restrict__ ss)
{
    int t = blockIdx.x * 256 + threadIdx.x;   // 0 .. 65535
    int p = t >> 9, w = t & 511;
    int q = w >> 7, r = (w >> 3) & 15, j = w & 7;
    {   // w1: M=128, K=512 -> 8 x 16 panels
        int mt = p >> 4, kt = p & 15;
        int m = mt * 16 + r, k = kt * 32 + q * 8 + j;
        w1p_rgb[t] = f2bf(w1_rgb[m * C_ + k]);
        w1p_inf[t] = f2bf(w1_inf[m * C_ + k]);
    }
    {   // w2: M=512, K=128 -> 32 x 4 panels
        int mt = p >> 2, kt = p & 3;
        int m = mt * 16 + r, k = kt * 32 + q * 8 + j;
        w2p_rgb[t] = f2bf(w2_rgb[m * HID_ + k]);
        w2p_inf[t] = f2bf(w2_inf[m * HID_ + k]);
    }
    if (t < 128) {
        float sc = g_rgb[t] * rsqrtf(rv_rgb[t] + EPS_);
        ss[t] = sc; ss[128 + t] = b_rgb[t] - rm_rgb[t] * sc;
    } else if (t < 256) {
        int i = t - 128;
        float sc = g_inf[i] * rsqrtf(rv_inf[i] + EPS_);
        ss[256 + i] = sc; ss[384 + i] = b_inf[i] - rm_inf[i] * sc;
    }
}

// ---------------------------------------------------------------------------
// Fused: per block (sample b, 64-pixel tile):
//   stage1: h(128x64) = w1_sel @ x-tile (K=512), BN+ReLU -> hlds bf16
//     vmem ISSUE ORDER per iter: af(k) FIRST, then x(k+1) prefetch, pinned by
//     sched_barrier. MFMA(k) then waits vmcnt(16) (af landed, prefetch still
//     in flight). Previous rounds issued af last -> MFMA's wait implied
//     vmcnt(0) (FIFO) and killed the pipeline.
//   stage2: out(512x64) = w2_sel @ h, in FOUR passes of acc[2][4] (32 acc
//     regs, was 64). Unified VGPR+AGPR peak ~116 <= 128 -> 4 waves/SIMD
//     (was ~148 -> 2 waves/SIMD, Occupancy 26%). Occupancy is the lever:
//     with 2 blocks/CU, stage-1 fetch and stage-2 store phases cannot
//     overlap across blocks and both memory pipes idle ~60%.
//   LDS: hlds ALIASES the two xlds buffers -> 18432 B total.
// ---------------------------------------------------------------------------
__global__ __launch_bounds__(256) void fused_kernel(
    const float* __restrict__ x, const int* __restrict__ mod,
    const short* __restrict__ w1p_rgb, const short* __restrict__ w1p_inf,
    const short* __restrict__ w2p_rgb, const short* __restrict__ w2p_inf,
    const float* __restrict__ ss, float* __restrict__ out)
{
    __shared__ short smem[2 * PT * XP];  // 2 x-chunk buffers; reused as hlds
    short* hlds = smem;                  // [pixel][hid(128)] pitch 136; 8704<=9216

    const int tid  = threadIdx.x;
    const int lane = tid & 63;
    const int wave = tid >> 6;
    const int i16  = lane & 15;   // frag col index
    const int q    = lane >> 4;   // frag quad
    const int b    = blockIdx.y;
    const int p0   = blockIdx.x * PT;

    const int is_rgb = (mod[b] == 1);
    const short* __restrict__ w1p = is_rgb ? w1p_rgb : w1p_inf;
    const short* __restrict__ w2p = is_rgb ? w2p_rgb : w2p_inf;
    const float* __restrict__ scale = ss + (is_rgb ? 0 : 256);
    const float* __restrict__ shift = scale + 128;

    // ---- Stage 1: wave handles hid rows [wave*32, wave*32+32) = 2 M-tiles ----
    f32x4 acc1[2][4];
    #pragma unroll
    for (int mt = 0; mt < 2; ++mt)
        #pragma unroll
        for (int nt = 0; nt < 4; ++nt)
            acc1[mt][nt] = (f32x4){0.f, 0.f, 0.f, 0.f};

    const int px = tid & 63;          // staging: this thread's pixel
    const int cg = tid >> 6;          // staging: channel group (16 ch each)
    const float* xbase = x + ((size_t)b * C_) * HW_ + p0 + px;

    // prologue: issue chunk-0 loads into registers (fp32, converted at use)
    float xr[16];
    #pragma unroll
    for (int it = 0; it < 4; ++it) {
        int c = cg * 16 + it * 4;
        xr[it * 4 + 0] = xbase[(size_t)(c + 0) * HW_];
        xr[it * 4 + 1] = xbase[(size_t)(c + 1) * HW_];
        xr[it * 4 + 2] = xbase[(size_t)(c + 2) * HW_];
        xr[it * 4 + 3] = xbase[(size_t)(c + 3) * HW_];
    }

    #pragma unroll 2
    for (int kc = 0; kc < C_; kc += 64) {
        short* xw = &smem[((kc >> 6) & 1) * (PT * XP)];

        // convert + write current chunk (vmcnt wait for xr lands here)
        #pragma unroll
        for (int it = 0; it < 4; ++it) {
            int c = cg * 16 + it * 4;
            short4 pk = make_short4(f2bf(xr[it * 4 + 0]), f2bf(xr[it * 4 + 1]),
                                    f2bf(xr[it * 4 + 2]), f2bf(xr[it * 4 + 3]));
            *(short4*)(&xw[px * XP + c]) = pk;
        }

        // af FIRST (consumed by THIS iter's MFMA; must be older than the
        // prefetch in the vmem FIFO so MFMA can wait vmcnt(16), not 0)
        frag8 af[2][2];
        #pragma unroll
        for (int kk = 0; kk < 2; ++kk) {
            int kt = (kc >> 5) + kk;
            #pragma unroll
            for (int mt = 0; mt < 2; ++mt) {
                int mtg = wave * 2 + mt;
                af[kk][mt] = *(const frag8*)(w1p + ((mtg * 16 + kt) << 9) + lane * 8);
            }
        }
        __builtin_amdgcn_sched_barrier(0);   // pin: af issues before prefetch

        // x(k+1) prefetch — newest in FIFO; stays in flight through the
        // barrier and the MFMA phase, drained at next iter's converts
        if (kc + 64 < C_) {
            #pragma unroll
            for (int it = 0; it < 4; ++it) {
                int c = kc + 64 + cg * 16 + it * 4;
                xr[it * 4 + 0] = xbase[(size_t)(c + 0) * HW_];
                xr[it * 4 + 1] = xbase[(size_t)(c + 1) * HW_];
                xr[it * 4 + 2] = xbase[(size_t)(c + 2) * HW_];
                xr[it * 4 + 3] = xbase[(size_t)(c + 3) * HW_];
            }
        }

        BARRIER_KEEP_VMEM();   // ds_writes visible; prefetch survives

        #pragma unroll
        for (int kk = 0; kk < 2; ++kk) {
            frag8 bfr[4];
            #pragma unroll
            for (int nt = 0; nt < 4; ++nt)
                bfr[nt] = *(const frag8*)(&xw[(nt * 16 + i16) * XP + kk * 32 + q * 8]);
            #pragma unroll
            for (int mt = 0; mt < 2; ++mt)
                #pragma unroll
                for (int nt = 0; nt < 4; ++nt)
                    acc1[mt][nt] = __builtin_amdgcn_mfma_f32_16x16x32_bf16(
                        af[kk][mt], bfr[nt], acc1[mt][nt], 0, 0, 0);
        }
        // no trailing barrier: double-buffer. Iter k+2's write to this buffer
        // is ordered after barrier(k+1); each wave's lgkmcnt(0) at barrier
        // k+1 covers its iter-k LDS reads.
    }

    // all waves must be done reading smem-as-xlds before hlds overwrites it
    __syncthreads();

    // ---- BN + ReLU -> hlds (bf16, pixel-major) ----
    #pragma unroll
    for (int mt = 0; mt < 2; ++mt) {
        int mbase = wave * 32 + mt * 16 + q * 4;
        float s0 = scale[mbase + 0], s1 = scale[mbase + 1];
        float s2 = scale[mbase + 2], s3 = scale[mbase + 3];
        float h0 = shift[mbase + 0], h1 = shift[mbase + 1];
        float h2 = shift[mbase + 2], h3 = shift[mbase + 3];
        #pragma unroll
        for (int nt = 0; nt < 4; ++nt) {
            int p = nt * 16 + i16;
            float v0 = fmaxf(acc1[mt][nt][0] * s0 + h0, 0.f);
            float v1 = fmaxf(acc1[mt][nt][1] * s1 + h1, 0.f);
            float v2 = fmaxf(acc1[mt][nt][2] * s2 + h2, 0.f);
            float v3 = fmaxf(acc1[mt][nt][3] * s3 + h3, 0.f);
            short4 pk = make_short4(f2bf(v0), f2bf(v1), f2bf(v2), f2bf(v3));
            *(short4*)(&hlds[p * HP + mbase]) = pk;
        }
    }
    __syncthreads();

    // ---- Stage 2: out(512x64); FOUR passes, 2 M-tiles x 4 N-tiles each ----
    // acc footprint 32 regs/pass (was 64) -> unified VGPR+AGPR peak <=128
    #pragma unroll 1
    for (int pass = 0; pass < 4; ++pass) {
        f32x4 acc2[2][4];
        #pragma unroll
        for (int mt = 0; mt < 2; ++mt)
            #pragma unroll
            for (int nt = 0; nt < 4; ++nt)
                acc2[mt][nt] = (f32x4){0.f, 0.f, 0.f, 0.f};

        #pragma unroll
        for (int kt = 0; kt < 4; ++kt) {
            frag8 af[2], bfr[4];
            #pragma unroll
            for (int mt = 0; mt < 2; ++mt) {
                int mtg = pass * 8 + wave * 2 + mt;
                af[mt] = *(const frag8*)(w2p + ((mtg * 4 + kt) << 9) + lane * 8);
            }
            #pragma unroll
            for (int nt = 0; nt < 4; ++nt)
                bfr[nt] = *(const frag8*)(&hlds[(nt * 16 + i16) * HP + kt * 32 + q * 8]);
            #pragma unroll
            for (int mt = 0; mt < 2; ++mt)
                #pragma unroll
                for (int nt = 0; nt < 4; ++nt)
                    acc2[mt][nt] = __builtin_amdgcn_mfma_f32_16x16x32_bf16(
                        af[mt], bfr[nt], acc2[mt][nt], 0, 0, 0);
        }
        // store fp32
        #pragma unroll
        for (int mt = 0; mt < 2; ++mt) {
            int mrow = (pass * 8 + wave * 2 + mt) * 16 + q * 4;
            #pragma unroll
            for (int nt = 0; nt < 4; ++nt) {
                int col = p0 + nt * 16 + i16;
                float* op = out + ((size_t)(b * C_ + mrow)) * HW_ + col;
                op[0 * HW_] = acc2[mt][nt][0];
                op[1 * HW_] = acc2[mt][nt][1];
                op[2 * HW_] = acc2[mt][nt][2];
                op[3 * HW_] = acc2[mt][nt][3];
            }
        }
    }
}

extern "C" void kernel_launch(void* const* d_in, const int* in_sizes, int n_in,
                              void* d_out, int out_size, void* d_ws, size_t ws_size,
                              hipStream_t stream) {
    const float* x      = (const float*)d_in[0];
    const int*   mod    = (const int*)d_in[1];
    const float* w1_rgb = (const float*)d_in[2];
    const float* rm_rgb = (const float*)d_in[3];
    const float* rv_rgb = (const float*)d_in[4];
    const float* g_rgb  = (const float*)d_in[5];
    const float* b_rgb  = (const float*)d_in[6];
    const float* w2_rgb = (const float*)d_in[7];
    const float* w1_inf = (const float*)d_in[8];
    const float* rm_inf = (const float*)d_in[9];
    const float* rv_inf = (const float*)d_in[10];
    const float* g_inf  = (const float*)d_in[11];
    const float* b_inf  = (const float*)d_in[12];
    const float* w2_inf = (const float*)d_in[13];
    float* out = (float*)d_out;

    char* ws = (char*)d_ws;
    short* w1p_rgb = (short*)(ws + 0);
    short* w1p_inf = (short*)(ws + 131072);
    short* w2p_rgb = (short*)(ws + 262144);
    short* w2p_inf = (short*)(ws + 393216);
    float* ss      = (float*)(ws + 524288);   // 512 floats

    prep_kernel<<<256, 256, 0, stream>>>(
        w1_rgb, w2_rgb, w1_inf, w2_inf,
        rm_rgb, rv_rgb, g_rgb, b_rgb,
        rm_inf, rv_inf, g_inf, b_inf,
        w1p_rgb, w1p_inf, w2p_rgb, w2p_inf, ss);

    dim3 grid(HW_ / PT, B_);
    fused_kernel<<<grid, 256, 0, stream>>>(
        x, mod, w1p_rgb, w1p_inf, w2p_rgb, w2p_inf, ss, out);
}